// Round 16
// baseline (122.887 us; speedup 1.0000x reference)
//
#include <hip/hip_runtime.h>
#include <cstdint>
#include <cstddef>

// Sizes: B=16, T=8, K=4, DIN=9408, H1=1024, F=512, MH=128

typedef float f2_t __attribute__((ext_vector_type(2)));
typedef float f4_t __attribute__((ext_vector_type(4)));

// ---------------- 4x4 average pool: x(16,3,224,224) -> xp(16,9408) ----------------
__global__ void pool_kernel(const float* __restrict__ x, float* __restrict__ xp) {
  int idx = blockIdx.x * 256 + threadIdx.x;      // 150528 total
  int bc = idx / 3136;
  int r  = idx - bc * 3136;
  int i  = r / 56;
  int j  = r - i * 56;
  const float* src = x + ((size_t)bc * 224 + 4 * i) * 224 + 4 * j;
  float s = 0.f;
#pragma unroll
  for (int rr = 0; rr < 4; ++rr) {
    float4 v = *reinterpret_cast<const float4*>(src + rr * 224);
    s += v.x + v.y + v.z + v.w;
  }
  xp[idx] = s * 0.0625f;
}

// ---------------- software-pipelined GEMM inner pipe (even AND odd NG) ----------------
// acc[b][v] += sum_{kk<KC} a_s[kk*20+b] * B[kk][j]  (B rows stride N)
template<int KC, int VEC, int UF, int NT>
__device__ __forceinline__ void gemm_pipe(
    const float* a_s, const float* Brow, int N, float (&acc)[16][VEC])
{
  static_assert(KC % UF == 0, "");
  constexpr int NG = KC / UF;
  static_assert(NG >= 2, "");
  float w0[UF][VEC], w1[UF][VEC];

  auto loadg = [&](float (&W)[UF][VEC], int kb) {
#pragma unroll
    for (int u = 0; u < UF; ++u) {
      const float* p = Brow + (size_t)(kb + u) * N;
      if constexpr (VEC == 2) {
        f2_t v;
        if constexpr (NT) v = __builtin_nontemporal_load(reinterpret_cast<const f2_t*>(p));
        else              v = *reinterpret_cast<const f2_t*>(p);
        W[u][0] = v.x; W[u][1] = v.y;
      } else {
        f4_t v;
        if constexpr (NT) v = __builtin_nontemporal_load(reinterpret_cast<const f4_t*>(p));
        else              v = *reinterpret_cast<const f4_t*>(p);
        W[u][0] = v.x; W[u][1] = v.y; W[u][2] = v.z; W[u][3] = v.w;
      }
    }
  };
  auto comp = [&](const float (&W)[UF][VEC], int kb) {
#pragma unroll
    for (int u = 0; u < UF; ++u) {
      int kk = kb + u;
      const float4 a0 = *reinterpret_cast<const float4*>(&a_s[kk * 20 + 0]);
      const float4 a1 = *reinterpret_cast<const float4*>(&a_s[kk * 20 + 4]);
      const float4 a2 = *reinterpret_cast<const float4*>(&a_s[kk * 20 + 8]);
      const float4 a3 = *reinterpret_cast<const float4*>(&a_s[kk * 20 + 12]);
      const float av[16] = {a0.x, a0.y, a0.z, a0.w, a1.x, a1.y, a1.z, a1.w,
                            a2.x, a2.y, a2.z, a2.w, a3.x, a3.y, a3.z, a3.w};
#pragma unroll
      for (int b = 0; b < 16; ++b)
#pragma unroll
        for (int v = 0; v < VEC; ++v)
          acc[b][v] = fmaf(av[b], W[u][v], acc[b][v]);
    }
  };

  loadg(w0, 0);
  if constexpr (NG % 2 == 0) {
#pragma unroll 1
    for (int g = 0; g + 2 < NG; g += 2) {
      loadg(w1, (g + 1) * UF);
      comp(w0, g * UF);
      loadg(w0, (g + 2) * UF);
      comp(w1, (g + 1) * UF);
    }
    loadg(w1, (NG - 1) * UF);
    comp(w0, (NG - 2) * UF);
    comp(w1, (NG - 1) * UF);
  } else {
#pragma unroll 1
    for (int g = 0; g + 3 < NG; g += 2) {
      loadg(w1, (g + 1) * UF);
      comp(w0, g * UF);
      loadg(w0, (g + 2) * UF);
      comp(w1, (g + 1) * UF);
    }
    loadg(w1, (NG - 2) * UF);
    comp(w0, (NG - 3) * UF);
    loadg(w0, (NG - 1) * UF);
    comp(w1, (NG - 2) * UF);
    comp(w0, (NG - 1) * UF);
  }
}

// ---------------- gbig5: G3 (512 half-chunks) + G1 (64 chunks), uniform KC=147 ------
// Round-16 change vs gbig4: chunk split 294->147 so grid = 576 uniform blocks
// (2.25/CU): EVERY CU holds >=2 blocks = 2 waves/SIMD (round-8 lesson; round-15's
// 368-block grid left 144 CUs at 1 wave/SIMD). VEC=4 16 B/lane kept. NO forced
// min-waves (round-12 lesson: launch_bounds(256,3) caused spills at ~150 VGPR).
__global__ __launch_bounds__(256) void gbig5_kernel(
    const float* __restrict__ xp,
    const float* __restrict__ W1,
    const float* __restrict__ dW1,
    float* __restrict__ P1, float* __restrict__ P3)
{
  __shared__ float a_s[147 * 20];   // 11.8 KB
  const int tid = threadIdx.x;

  const float* Bb;
  int il;
  float* Pout;
  if (blockIdx.x < 512) {
    // G3 half-chunk: t = c>>6, il = (c&63)*147
    const int c = blockIdx.x;
    const int t = c >> 6;
    il = (c & 63) * 147;
    Bb = dW1 + ((size_t)t * 9408 + il) * 1024;
    Pout = P3 + (size_t)c * 16 * 1024;
  } else {
    // G1 chunk: il = c*147
    const int c = blockIdx.x - 512;
    il = c * 147;
    Bb = W1 + (size_t)il * 1024;
    Pout = P1 + (size_t)c * 16 * 1024;
  }

  for (int idx = tid; idx < 16 * 147; idx += 256) {
    int b = idx / 147, kk = idx - b * 147;
    a_s[kk * 20 + b] = xp[(size_t)b * 9408 + il + kk];
  }
  __syncthreads();

  const int j0 = tid * 4;
  float acc[16][4];
#pragma unroll
  for (int b = 0; b < 16; ++b)
#pragma unroll
    for (int v = 0; v < 4; ++v) acc[b][v] = 0.f;

  gemm_pipe<147, 4, 7, 1>(a_s, Bb + j0, 1024, acc);

  float* Pb = Pout + j0;
#pragma unroll
  for (int b = 0; b < 16; ++b) {
    f4_t v = {acc[b][0], acc[b][1], acc[b][2], acc[b][3]};
    __builtin_nontemporal_store(v, reinterpret_cast<f4_t*>(Pb));
    Pb += 1024;
  }
}

// ---------------- rg12: R1 + G2 fused. 256 blocks x 256 thr ----------------
// Block (b=blk>>4, jg=blk&15): reduce P1 over 64 chunks (16 slices x CPS=4) for
// 64 cols -> z1, t1 (LDS). Then G2 row-b: stream W2[jg*64..][512] -> P2[jg][b][512].
__global__ __launch_bounds__(256) void rg12_kernel(
    const float* __restrict__ P1, const float* __restrict__ b1,
    const float* __restrict__ W2,
    float* __restrict__ z1, float* __restrict__ P2)
{
  __shared__ float4 r[16][17];
  __shared__ float t1s[64];
  const int blk = blockIdx.x;
  const int b = blk >> 4, jg = blk & 15;
  const int fl = threadIdx.x & 15, s = threadIdx.x >> 4;
  const int f = blk * 64 + fl * 4;          // = b*1024 + jg*64 + fl*4

  const f4_t* p = reinterpret_cast<const f4_t*>(P1 + (size_t)s * 4 * 16384 + f);
  float sx = 0.f, sy = 0.f, sz = 0.f, sw = 0.f;
#pragma unroll
  for (int cc = 0; cc < 4; ++cc) {
    f4_t v = __builtin_nontemporal_load(p);
    sx += v.x; sy += v.y; sz += v.z; sw += v.w;
    p += 4096;                              // 16384/4
  }
  r[s][fl] = make_float4(sx, sy, sz, sw);
  __syncthreads();

  if (s == 0) {
    float vx = 0.f, vy = 0.f, vz = 0.f, vw = 0.f;
#pragma unroll
    for (int i = 0; i < 16; ++i) {
      float4 t = r[i][fl];
      vx += t.x; vy += t.y; vz += t.z; vw += t.w;
    }
    float4 bb = *reinterpret_cast<const float4*>(b1 + (f & 1023));
    float4 z = make_float4(vx + bb.x, vy + bb.y, vz + bb.z, vw + bb.w);
    *reinterpret_cast<float4*>(z1 + f) = z;
    *reinterpret_cast<float4*>(&t1s[fl * 4]) =
        make_float4(fmaxf(z.x, 0.f), fmaxf(z.y, 0.f), fmaxf(z.z, 0.f), fmaxf(z.w, 0.f));
  }
  __syncthreads();

  const int j = threadIdx.x * 2;
  const float* w = W2 + (size_t)(jg * 64) * 512 + j;
  float a0 = 0.f, a1 = 0.f;
#pragma unroll 8
  for (int kk = 0; kk < 64; ++kk) {
    f2_t wv = *reinterpret_cast<const f2_t*>(w);
    w += 512;
    float tv = t1s[kk];
    a0 = fmaf(tv, wv.x, a0);
    a1 = fmaf(tv, wv.y, a1);
  }
  f2_t o = {a0, a1};
  __builtin_nontemporal_store(o, reinterpret_cast<f2_t*>(P2 + ((size_t)jg * 16 + b) * 512 + j));
}

// ---------------- split-K skinny GEMM (M=16) -- used for G4 ----------------
template<int KC, int VEC, int UF, int NT, int BS>
__global__ __launch_bounds__(BS) void skinny_gemm(
    const float* __restrict__ A, int ldA,
    const float* __restrict__ B,
    const float* __restrict__ A2, int ldA2,
    const float* __restrict__ B2,
    int chunkSplit, int chunksPerT,
    const float* __restrict__ coefs4,
    int N, float* __restrict__ P)
{
  __shared__ float a_s[KC * 20];
  const int c = blockIdx.x, tid = threadIdx.x;

  const float* Ab;
  const float* Bb;
  int lda, iLoc0, t = 0;
  bool scaled = false;
  if (c < chunkSplit) {
    Ab = A; lda = ldA;
    if (chunksPerT > 0) {
      t = c / chunksPerT;
      iLoc0 = (c - t * chunksPerT) * KC;
    } else {
      iLoc0 = c * KC;
    }
    scaled = (coefs4 != nullptr);
    Bb = B + (size_t)c * KC * N;
  } else {
    Ab = A2; lda = ldA2;
    iLoc0 = (c - chunkSplit) * KC;
    Bb = B2 + (size_t)iLoc0 * N;
  }

  for (int b = 0; b < 16; ++b) {
    float s = scaled ? coefs4[b * 32 + t * 4] : 1.f;
    const float* Arow = Ab + (size_t)b * lda + iLoc0;
    for (int kk = tid; kk < KC; kk += BS)
      a_s[kk * 20 + b] = s * Arow[kk];
  }
  __syncthreads();

  const int j0 = (blockIdx.y * BS + tid) * VEC;
  float acc[16][VEC];
#pragma unroll
  for (int b = 0; b < 16; ++b)
#pragma unroll
    for (int v = 0; v < VEC; ++v) acc[b][v] = 0.f;

  gemm_pipe<KC, VEC, UF, NT>(a_s, Bb + j0, N, acc);

  float* Pb = P + (size_t)c * 16 * N + j0;
#pragma unroll
  for (int b = 0; b < 16; ++b) {
    if constexpr (VEC == 2) {
      f2_t v = {acc[b][0], acc[b][1]};
      __builtin_nontemporal_store(v, reinterpret_cast<f2_t*>(Pb));
    } else {
      f4_t v = {acc[b][0], acc[b][1], acc[b][2], acc[b][3]};
      __builtin_nontemporal_store(v, reinterpret_cast<f4_t*>(Pb));
    }
    Pb += N;
  }
}

// ---------------- fused reduce + epilogue (float4 NT loads, 16 slices x 16 cols) ------
// MODE 3: h=relu(z1+cW1-scaled-sum+db1 term)   MODE 4: out
template<int NCH, int MODE, int FTOT>
__global__ __launch_bounds__(256) void reduce4(
    const float* __restrict__ P,
    const float* __restrict__ bias,      // z1(M3), b2(M4)
    const float* __restrict__ coefs,
    const float* __restrict__ dvec,      // db1(M3), db2(M4)
    float* __restrict__ o1)
{
  constexpr int CPS = NCH / 16;
  static_assert(NCH % 16 == 0, "");
  __shared__ float4 r[16][17];
  const int fl = threadIdx.x & 15, s = threadIdx.x >> 4;
  const int f = blockIdx.x * 64 + fl * 4;

  const f4_t* p = reinterpret_cast<const f4_t*>(P + (size_t)s * CPS * FTOT + f);
  float sx = 0.f, sy = 0.f, sz = 0.f, sw = 0.f;
#pragma unroll 8
  for (int cc = 0; cc < CPS; ++cc) {
    f4_t v = __builtin_nontemporal_load(p);
    sx += v.x; sy += v.y; sz += v.z; sw += v.w;
    p += FTOT / 4;
  }
  if constexpr (MODE == 3) {
    int b = f >> 10;
    float sc = coefs[b * 32 + (s >> 1) * 4];   // cW1[b, t = s/2] (64 chunks/t = 2 slices/t)
    sx *= sc; sy *= sc; sz *= sc; sw *= sc;
  }
  r[s][fl] = make_float4(sx, sy, sz, sw);
  __syncthreads();

  if (s == 0) {
    float vx = 0.f, vy = 0.f, vz = 0.f, vw = 0.f;
#pragma unroll
    for (int i = 0; i < 16; ++i) {
      float4 t = r[i][fl];
      vx += t.x; vy += t.y; vz += t.z; vw += t.w;
    }
    if constexpr (MODE == 3) {
      int b = f >> 10, j = f & 1023;
      float4 zz = *reinterpret_cast<const float4*>(bias + f);   // z1
      float zx = vx + zz.x, zy = vy + zz.y, zzc = vz + zz.z, zw = vw + zz.w;
#pragma unroll
      for (int t = 0; t < 8; ++t) {
        float c1 = coefs[b * 32 + t * 4 + 1];
        float4 d = *reinterpret_cast<const float4*>(dvec + t * 1024 + j);
        zx = fmaf(c1, d.x, zx); zy = fmaf(c1, d.y, zy);
        zzc = fmaf(c1, d.z, zzc); zw = fmaf(c1, d.w, zw);
      }
      *reinterpret_cast<float4*>(o1 + f) =
          make_float4(fmaxf(zx, 0.f), fmaxf(zy, 0.f), fmaxf(zzc, 0.f), fmaxf(zw, 0.f));
    } else {
      int b = f >> 9, k = f & 511;
      float4 bb = *reinterpret_cast<const float4*>(bias + k);   // b2
      float zx = vx + bb.x, zy = vy + bb.y, zzc = vz + bb.z, zw = vw + bb.w;
#pragma unroll
      for (int t = 0; t < 8; ++t) {
        float c3 = coefs[b * 32 + t * 4 + 3];
        float4 d = *reinterpret_cast<const float4*>(dvec + t * 512 + k);
        zx = fmaf(c3, d.x, zx); zy = fmaf(c3, d.y, zy);
        zzc = fmaf(c3, d.z, zzc); zw = fmaf(c3, d.w, zw);
      }
      *reinterpret_cast<float4*>(o1 + f) = make_float4(zx, zy, zzc, zw);
    }
  }
}

// ---------------- tail2: R2 + mcoef fused. One block per b (16 x 512 thr). ----------
__global__ __launch_bounds__(512) void tail2_kernel(
    const float* __restrict__ P2, const float* __restrict__ b2,
    const float* __restrict__ mW1, const float* __restrict__ mb1,
    const float* __restrict__ mW2, const float* __restrict__ mb2,
    float* __restrict__ coefs)
{
  __shared__ float bs[512];
  __shared__ float pm[4][129];
  __shared__ float ms[128];
  __shared__ float p3[16][33];
  const int b = blockIdx.x, tid = threadIdx.x;

  // phase 1: base[b][k] = b2[k] + sum over 16 chunks
  float s = b2[tid];
  const float* p = P2 + b * 512 + tid;
#pragma unroll
  for (int c = 0; c < 16; ++c) { s += *p; p += 8192; }
  bs[tid] = s;
  __syncthreads();

  // phase 2: m[col], k-split 4 ways
  {
    int col = tid & 127, kq = tid >> 7;
    const float* br = &bs[kq * 128];
    const float* w = mW1 + (size_t)(kq * 128) * 128 + col;
    float m0 = 0.f, m1 = 0.f, m2 = 0.f, m3 = 0.f;
    for (int k = 0; k < 128; k += 4) {
      m0 = fmaf(br[k + 0], w[(k + 0) * 128], m0);
      m1 = fmaf(br[k + 1], w[(k + 1) * 128], m1);
      m2 = fmaf(br[k + 2], w[(k + 2) * 128], m2);
      m3 = fmaf(br[k + 3], w[(k + 3) * 128], m3);
    }
    pm[kq][col] = (m0 + m1) + (m2 + m3);
  }
  __syncthreads();
  if (tid < 128)
    ms[tid] = fmaxf(mb1[tid] + (pm[0][tid] + pm[1][tid]) + (pm[2][tid] + pm[3][tid]), 0.f);
  __syncthreads();

  // phase 3: coefs[o], k-split 16 ways
  {
    int o = tid & 31, kq = tid >> 5;
    float a = 0.f;
#pragma unroll
    for (int kk = 0; kk < 8; ++kk)
      a = fmaf(ms[kq * 8 + kk], mW2[(kq * 8 + kk) * 32 + o], a);
    p3[kq][o] = a;
  }
  __syncthreads();
  if (tid < 32) {
    float a = mb2[tid];
#pragma unroll
    for (int q = 0; q < 16; ++q) a += p3[q][tid];
    coefs[b * 32 + tid] = a;
  }
}

extern "C" void kernel_launch(void* const* d_in, const int* in_sizes, int n_in,
                              void* d_out, int out_size, void* d_ws, size_t ws_size,
                              hipStream_t stream) {
  const float* x   = (const float*)d_in[0];
  const float* W1  = (const float*)d_in[1];
  const float* b1  = (const float*)d_in[2];
  const float* W2  = (const float*)d_in[3];
  const float* b2  = (const float*)d_in[4];
  const float* dW1 = (const float*)d_in[5];
  const float* db1 = (const float*)d_in[6];
  const float* dW2 = (const float*)d_in[7];
  const float* db2 = (const float*)d_in[8];
  const float* mW1 = (const float*)d_in[9];
  const float* mb1 = (const float*)d_in[10];
  const float* mW2 = (const float*)d_in[11];
  const float* mb2 = (const float*)d_in[12];
  float* out = (float*)d_out;

  float* ws    = (float*)d_ws;
  float* xp    = ws;                 // 150528
  float* z1    = xp + 150528;        // 16384
  float* coefs = z1 + 16384;         // 512
  float* h     = coefs + 512;        // 16384
  float* P1    = h + 16384;          // 64*16*1024  = 1048576
  float* P2    = P1 + 1048576;       // 16*16*512   = 131072
  float* P3    = P2 + 131072;        // 512*16*1024 = 8388608
  float* P4    = P3 + 8388608;       // 288*16*512  = 2359296
  // total ~12.1M floats ~ 48 MB

  // 1) xp = pool(x)
  pool_kernel<<<588, 256, 0, stream>>>(x, xp);

  // 2) gbig5: G3 (512 half-chunks KC=147) + G1 (64 chunks KC=147); 576 uniform
  //    blocks = 2.25/CU -> every CU >= 2 waves/SIMD, VEC=4 16 B/lane streams
  gbig5_kernel<<<576, 256, 0, stream>>>(xp, W1, dW1, P1, P3);

  // 3) rg12: R1 (64 chunks) + G2 -> z1, P2
  rg12_kernel<<<256, 256, 0, stream>>>(P1, b1, W2, z1, P2);

  // 4) tail2: R2 + mcoef -> coefs
  tail2_kernel<<<16, 512, 0, stream>>>(P2, b2, mW1, mb1, mW2, mb2, coefs);

  // 5) R3 (cW1 scale per slice, 512 chunks) -> h
  reduce4<512, 3, 16384><<<256, 256, 0, stream>>>(P3, z1, coefs, db1, h);

  // 6) G4: h @ {dW2 scaled, W2} -> P4
  skinny_gemm<32, 2, 8, 1, 256><<<dim3(288, 1), 256, 0, stream>>>(
      h, 1024, dW2, h, 1024, W2, 256, 32, coefs + 2, 512, P4);

  // 7) R4 -> out
  reduce4<288, 4, 8192><<<128, 256, 0, stream>>>(P4, b2, coefs, db2, out);
}

// Round 17
// 116.548 us; speedup vs baseline: 1.0544x; 1.0544x over previous
//
#include <hip/hip_runtime.h>
#include <cstdint>
#include <cstddef>

// Sizes: B=16, T=8, K=4, DIN=9408, H1=1024, F=512, MH=128

typedef float f2_t __attribute__((ext_vector_type(2)));
typedef float f4_t __attribute__((ext_vector_type(4)));

// ---------------- 4x4 average pool: x(16,3,224,224) -> xp(16,9408) ----------------
__global__ void pool_kernel(const float* __restrict__ x, float* __restrict__ xp) {
  int idx = blockIdx.x * 256 + threadIdx.x;      // 150528 total
  int bc = idx / 3136;
  int r  = idx - bc * 3136;
  int i  = r / 56;
  int j  = r - i * 56;
  const float* src = x + ((size_t)bc * 224 + 4 * i) * 224 + 4 * j;
  float s = 0.f;
#pragma unroll
  for (int rr = 0; rr < 4; ++rr) {
    float4 v = *reinterpret_cast<const float4*>(src + rr * 224);
    s += v.x + v.y + v.z + v.w;
  }
  xp[idx] = s * 0.0625f;
}

// ---------------- software-pipelined GEMM inner pipe (even AND odd NG) ----------------
// acc[b][v] += sum_{kk<KC} a_s[kk*20+b] * B[kk][j]  (B rows stride N)
template<int KC, int VEC, int UF, int NT>
__device__ __forceinline__ void gemm_pipe(
    const float* a_s, const float* Brow, int N, float (&acc)[16][VEC])
{
  static_assert(KC % UF == 0, "");
  constexpr int NG = KC / UF;
  static_assert(NG >= 2, "");
  float w0[UF][VEC], w1[UF][VEC];

  auto loadg = [&](float (&W)[UF][VEC], int kb) {
#pragma unroll
    for (int u = 0; u < UF; ++u) {
      const float* p = Brow + (size_t)(kb + u) * N;
      if constexpr (VEC == 2) {
        f2_t v;
        if constexpr (NT) v = __builtin_nontemporal_load(reinterpret_cast<const f2_t*>(p));
        else              v = *reinterpret_cast<const f2_t*>(p);
        W[u][0] = v.x; W[u][1] = v.y;
      } else {
        f4_t v;
        if constexpr (NT) v = __builtin_nontemporal_load(reinterpret_cast<const f4_t*>(p));
        else              v = *reinterpret_cast<const f4_t*>(p);
        W[u][0] = v.x; W[u][1] = v.y; W[u][2] = v.z; W[u][3] = v.w;
      }
    }
  };
  auto comp = [&](const float (&W)[UF][VEC], int kb) {
#pragma unroll
    for (int u = 0; u < UF; ++u) {
      int kk = kb + u;
      const float4 a0 = *reinterpret_cast<const float4*>(&a_s[kk * 20 + 0]);
      const float4 a1 = *reinterpret_cast<const float4*>(&a_s[kk * 20 + 4]);
      const float4 a2 = *reinterpret_cast<const float4*>(&a_s[kk * 20 + 8]);
      const float4 a3 = *reinterpret_cast<const float4*>(&a_s[kk * 20 + 12]);
      const float av[16] = {a0.x, a0.y, a0.z, a0.w, a1.x, a1.y, a1.z, a1.w,
                            a2.x, a2.y, a2.z, a2.w, a3.x, a3.y, a3.z, a3.w};
#pragma unroll
      for (int b = 0; b < 16; ++b)
#pragma unroll
        for (int v = 0; v < VEC; ++v)
          acc[b][v] = fmaf(av[b], W[u][v], acc[b][v]);
    }
  };

  loadg(w0, 0);
  if constexpr (NG % 2 == 0) {
#pragma unroll 1
    for (int g = 0; g + 2 < NG; g += 2) {
      loadg(w1, (g + 1) * UF);
      comp(w0, g * UF);
      loadg(w0, (g + 2) * UF);
      comp(w1, (g + 1) * UF);
    }
    loadg(w1, (NG - 1) * UF);
    comp(w0, (NG - 2) * UF);
    comp(w1, (NG - 1) * UF);
  } else {
#pragma unroll 1
    for (int g = 0; g + 3 < NG; g += 2) {
      loadg(w1, (g + 1) * UF);
      comp(w0, g * UF);
      loadg(w0, (g + 2) * UF);
      comp(w1, (g + 1) * UF);
    }
    loadg(w1, (NG - 2) * UF);
    comp(w0, (NG - 3) * UF);
    loadg(w0, (NG - 1) * UF);
    comp(w1, (NG - 2) * UF);
    comp(w0, (NG - 1) * UF);
  }
}

// ---------------- gbig6: G3 (256 blocks, first) + G1 (112 blocks) ----------------
// Round-17 single-variable change vs round-15's gbig4 (the 110 us champion):
// G3 UF 7 -> 14 (14 f4 NT loads = 14 KB in flight per wave) to fill the HBM
// queue across the vmcnt group boundary. Same chunks, same P1/P3, no forced
// min-waves. ~200 VGPR expected -> 2 waves/SIMD cap, no spill.
__global__ __launch_bounds__(256) void gbig6_kernel(
    const float* __restrict__ xp,
    const float* __restrict__ W1,
    const float* __restrict__ dW1,
    float* __restrict__ P1, float* __restrict__ P3)
{
  __shared__ float a_s[294 * 20];   // 23.5 KB
  const int tid = threadIdx.x;

  if (blockIdx.x < 256) {
    // ---- G3 chunk: t=c>>5, il=(c&31)*294; KC=294, VEC=4, UF=14 -> P3[c] ----
    const int c = blockIdx.x;
    const int t = c >> 5, il = (c & 31) * 294;
    for (int idx = tid; idx < 16 * 294; idx += 256) {
      int b = idx / 294, kk = idx - b * 294;
      a_s[kk * 20 + b] = xp[(size_t)b * 9408 + il + kk];
    }
    __syncthreads();

    const int j0 = tid * 4;
    float acc[16][4];
#pragma unroll
    for (int b = 0; b < 16; ++b)
#pragma unroll
      for (int v = 0; v < 4; ++v) acc[b][v] = 0.f;
    gemm_pipe<294, 4, 14, 1>(a_s, dW1 + ((size_t)t * 9408 + il) * 1024 + j0, 1024, acc);

    float* Pb = P3 + (size_t)c * 16 * 1024 + j0;
#pragma unroll
    for (int b = 0; b < 16; ++b) {
      f4_t v = {acc[b][0], acc[b][1], acc[b][2], acc[b][3]};
      __builtin_nontemporal_store(v, reinterpret_cast<f4_t*>(Pb));
      Pb += 1024;
    }
  } else {
    // ---- G1 chunk: KC=84, VEC=4, UF=7 -> P1[c] ----
    const int c = blockIdx.x - 256;
    for (int idx = tid; idx < 16 * 84; idx += 256) {
      int b = idx / 84, kk = idx - b * 84;
      a_s[kk * 20 + b] = xp[(size_t)b * 9408 + c * 84 + kk];
    }
    __syncthreads();

    const int j0 = tid * 4;
    float acc[16][4];
#pragma unroll
    for (int b = 0; b < 16; ++b)
#pragma unroll
      for (int v = 0; v < 4; ++v) acc[b][v] = 0.f;
    gemm_pipe<84, 4, 7, 1>(a_s, W1 + (size_t)c * 84 * 1024 + j0, 1024, acc);

    float* Pb = P1 + (size_t)c * 16 * 1024 + j0;
#pragma unroll
    for (int b = 0; b < 16; ++b) {
      f4_t v = {acc[b][0], acc[b][1], acc[b][2], acc[b][3]};
      __builtin_nontemporal_store(v, reinterpret_cast<f4_t*>(Pb));
      Pb += 1024;
    }
  }
}

// ---------------- rg12: R1 + G2 fused. 256 blocks x 256 thr ----------------
// Block (b=blk>>4, jg=blk&15): reduce P1 over 112 chunks (16 slices x CPS=7) for
// 64 cols -> z1, t1 (LDS). Then G2 row-b: stream W2[jg*64..][512] -> P2[jg][b][512].
__global__ __launch_bounds__(256) void rg12_kernel(
    const float* __restrict__ P1, const float* __restrict__ b1,
    const float* __restrict__ W2,
    float* __restrict__ z1, float* __restrict__ P2)
{
  __shared__ float4 r[16][17];
  __shared__ float t1s[64];
  const int blk = blockIdx.x;
  const int b = blk >> 4, jg = blk & 15;
  const int fl = threadIdx.x & 15, s = threadIdx.x >> 4;
  const int f = blk * 64 + fl * 4;          // = b*1024 + jg*64 + fl*4

  const f4_t* p = reinterpret_cast<const f4_t*>(P1 + (size_t)s * 7 * 16384 + f);
  float sx = 0.f, sy = 0.f, sz = 0.f, sw = 0.f;
#pragma unroll
  for (int cc = 0; cc < 7; ++cc) {
    f4_t v = __builtin_nontemporal_load(p);
    sx += v.x; sy += v.y; sz += v.z; sw += v.w;
    p += 4096;                              // 16384/4
  }
  r[s][fl] = make_float4(sx, sy, sz, sw);
  __syncthreads();

  if (s == 0) {
    float vx = 0.f, vy = 0.f, vz = 0.f, vw = 0.f;
#pragma unroll
    for (int i = 0; i < 16; ++i) {
      float4 t = r[i][fl];
      vx += t.x; vy += t.y; vz += t.z; vw += t.w;
    }
    float4 bb = *reinterpret_cast<const float4*>(b1 + (f & 1023));
    float4 z = make_float4(vx + bb.x, vy + bb.y, vz + bb.z, vw + bb.w);
    *reinterpret_cast<float4*>(z1 + f) = z;
    *reinterpret_cast<float4*>(&t1s[fl * 4]) =
        make_float4(fmaxf(z.x, 0.f), fmaxf(z.y, 0.f), fmaxf(z.z, 0.f), fmaxf(z.w, 0.f));
  }
  __syncthreads();

  const int j = threadIdx.x * 2;
  const float* w = W2 + (size_t)(jg * 64) * 512 + j;
  float a0 = 0.f, a1 = 0.f;
#pragma unroll 8
  for (int kk = 0; kk < 64; ++kk) {
    f2_t wv = *reinterpret_cast<const f2_t*>(w);
    w += 512;
    float tv = t1s[kk];
    a0 = fmaf(tv, wv.x, a0);
    a1 = fmaf(tv, wv.y, a1);
  }
  f2_t o = {a0, a1};
  __builtin_nontemporal_store(o, reinterpret_cast<f2_t*>(P2 + ((size_t)jg * 16 + b) * 512 + j));
}

// ---------------- split-K skinny GEMM (M=16) -- used for G4 ----------------
template<int KC, int VEC, int UF, int NT, int BS>
__global__ __launch_bounds__(BS) void skinny_gemm(
    const float* __restrict__ A, int ldA,
    const float* __restrict__ B,
    const float* __restrict__ A2, int ldA2,
    const float* __restrict__ B2,
    int chunkSplit, int chunksPerT,
    const float* __restrict__ coefs4,
    int N, float* __restrict__ P)
{
  __shared__ float a_s[KC * 20];
  const int c = blockIdx.x, tid = threadIdx.x;

  const float* Ab;
  const float* Bb;
  int lda, iLoc0, t = 0;
  bool scaled = false;
  if (c < chunkSplit) {
    Ab = A; lda = ldA;
    if (chunksPerT > 0) {
      t = c / chunksPerT;
      iLoc0 = (c - t * chunksPerT) * KC;
    } else {
      iLoc0 = c * KC;
    }
    scaled = (coefs4 != nullptr);
    Bb = B + (size_t)c * KC * N;
  } else {
    Ab = A2; lda = ldA2;
    iLoc0 = (c - chunkSplit) * KC;
    Bb = B2 + (size_t)iLoc0 * N;
  }

  for (int b = 0; b < 16; ++b) {
    float s = scaled ? coefs4[b * 32 + t * 4] : 1.f;
    const float* Arow = Ab + (size_t)b * lda + iLoc0;
    for (int kk = tid; kk < KC; kk += BS)
      a_s[kk * 20 + b] = s * Arow[kk];
  }
  __syncthreads();

  const int j0 = (blockIdx.y * BS + tid) * VEC;
  float acc[16][VEC];
#pragma unroll
  for (int b = 0; b < 16; ++b)
#pragma unroll
    for (int v = 0; v < VEC; ++v) acc[b][v] = 0.f;

  gemm_pipe<KC, VEC, UF, NT>(a_s, Bb + j0, N, acc);

  float* Pb = P + (size_t)c * 16 * N + j0;
#pragma unroll
  for (int b = 0; b < 16; ++b) {
    if constexpr (VEC == 2) {
      f2_t v = {acc[b][0], acc[b][1]};
      __builtin_nontemporal_store(v, reinterpret_cast<f2_t*>(Pb));
    } else {
      f4_t v = {acc[b][0], acc[b][1], acc[b][2], acc[b][3]};
      __builtin_nontemporal_store(v, reinterpret_cast<f4_t*>(Pb));
    }
    Pb += N;
  }
}

// ---------------- fused reduce + epilogue (float4 NT loads, 16 slices x 16 cols) ------
// MODE 3: h=relu(z1+cW1-scaled-sum+db1 term)   MODE 4: out
template<int NCH, int MODE, int FTOT>
__global__ __launch_bounds__(256) void reduce4(
    const float* __restrict__ P,
    const float* __restrict__ bias,      // z1(M3), b2(M4)
    const float* __restrict__ coefs,
    const float* __restrict__ dvec,      // db1(M3), db2(M4)
    float* __restrict__ o1)
{
  constexpr int CPS = NCH / 16;
  static_assert(NCH % 16 == 0, "");
  __shared__ float4 r[16][17];
  const int fl = threadIdx.x & 15, s = threadIdx.x >> 4;
  const int f = blockIdx.x * 64 + fl * 4;

  const f4_t* p = reinterpret_cast<const f4_t*>(P + (size_t)s * CPS * FTOT + f);
  float sx = 0.f, sy = 0.f, sz = 0.f, sw = 0.f;
#pragma unroll 8
  for (int cc = 0; cc < CPS; ++cc) {
    f4_t v = __builtin_nontemporal_load(p);
    sx += v.x; sy += v.y; sz += v.z; sw += v.w;
    p += FTOT / 4;
  }
  if constexpr (MODE == 3) {
    int b = f >> 10;
    float sc = coefs[b * 32 + (s >> 1) * 4];   // cW1[b, t = s/2] (32 chunks/t = 2 slices/t)
    sx *= sc; sy *= sc; sz *= sc; sw *= sc;
  }
  r[s][fl] = make_float4(sx, sy, sz, sw);
  __syncthreads();

  if (s == 0) {
    float vx = 0.f, vy = 0.f, vz = 0.f, vw = 0.f;
#pragma unroll
    for (int i = 0; i < 16; ++i) {
      float4 t = r[i][fl];
      vx += t.x; vy += t.y; vz += t.z; vw += t.w;
    }
    if constexpr (MODE == 3) {
      int b = f >> 10, j = f & 1023;
      float4 zz = *reinterpret_cast<const float4*>(bias + f);   // z1
      float zx = vx + zz.x, zy = vy + zz.y, zzc = vz + zz.z, zw = vw + zz.w;
#pragma unroll
      for (int t = 0; t < 8; ++t) {
        float c1 = coefs[b * 32 + t * 4 + 1];
        float4 d = *reinterpret_cast<const float4*>(dvec + t * 1024 + j);
        zx = fmaf(c1, d.x, zx); zy = fmaf(c1, d.y, zy);
        zzc = fmaf(c1, d.z, zzc); zw = fmaf(c1, d.w, zw);
      }
      *reinterpret_cast<float4*>(o1 + f) =
          make_float4(fmaxf(zx, 0.f), fmaxf(zy, 0.f), fmaxf(zzc, 0.f), fmaxf(zw, 0.f));
    } else {
      int b = f >> 9, k = f & 511;
      float4 bb = *reinterpret_cast<const float4*>(bias + k);   // b2
      float zx = vx + bb.x, zy = vy + bb.y, zzc = vz + bb.z, zw = vw + bb.w;
#pragma unroll
      for (int t = 0; t < 8; ++t) {
        float c3 = coefs[b * 32 + t * 4 + 3];
        float4 d = *reinterpret_cast<const float4*>(dvec + t * 512 + k);
        zx = fmaf(c3, d.x, zx); zy = fmaf(c3, d.y, zy);
        zzc = fmaf(c3, d.z, zzc); zw = fmaf(c3, d.w, zw);
      }
      *reinterpret_cast<float4*>(o1 + f) = make_float4(zx, zy, zzc, zw);
    }
  }
}

// ---------------- tail2: R2 + mcoef fused. One block per b (16 x 512 thr). ----------
__global__ __launch_bounds__(512) void tail2_kernel(
    const float* __restrict__ P2, const float* __restrict__ b2,
    const float* __restrict__ mW1, const float* __restrict__ mb1,
    const float* __restrict__ mW2, const float* __restrict__ mb2,
    float* __restrict__ coefs)
{
  __shared__ float bs[512];
  __shared__ float pm[4][129];
  __shared__ float ms[128];
  __shared__ float p3[16][33];
  const int b = blockIdx.x, tid = threadIdx.x;

  // phase 1: base[b][k] = b2[k] + sum over 16 chunks
  float s = b2[tid];
  const float* p = P2 + b * 512 + tid;
#pragma unroll
  for (int c = 0; c < 16; ++c) { s += *p; p += 8192; }
  bs[tid] = s;
  __syncthreads();

  // phase 2: m[col], k-split 4 ways
  {
    int col = tid & 127, kq = tid >> 7;
    const float* br = &bs[kq * 128];
    const float* w = mW1 + (size_t)(kq * 128) * 128 + col;
    float m0 = 0.f, m1 = 0.f, m2 = 0.f, m3 = 0.f;
    for (int k = 0; k < 128; k += 4) {
      m0 = fmaf(br[k + 0], w[(k + 0) * 128], m0);
      m1 = fmaf(br[k + 1], w[(k + 1) * 128], m1);
      m2 = fmaf(br[k + 2], w[(k + 2) * 128], m2);
      m3 = fmaf(br[k + 3], w[(k + 3) * 128], m3);
    }
    pm[kq][col] = (m0 + m1) + (m2 + m3);
  }
  __syncthreads();
  if (tid < 128)
    ms[tid] = fmaxf(mb1[tid] + (pm[0][tid] + pm[1][tid]) + (pm[2][tid] + pm[3][tid]), 0.f);
  __syncthreads();

  // phase 3: coefs[o], k-split 16 ways
  {
    int o = tid & 31, kq = tid >> 5;
    float a = 0.f;
#pragma unroll
    for (int kk = 0; kk < 8; ++kk)
      a = fmaf(ms[kq * 8 + kk], mW2[(kq * 8 + kk) * 32 + o], a);
    p3[kq][o] = a;
  }
  __syncthreads();
  if (tid < 32) {
    float a = mb2[tid];
#pragma unroll
    for (int q = 0; q < 16; ++q) a += p3[q][tid];
    coefs[b * 32 + tid] = a;
  }
}

extern "C" void kernel_launch(void* const* d_in, const int* in_sizes, int n_in,
                              void* d_out, int out_size, void* d_ws, size_t ws_size,
                              hipStream_t stream) {
  const float* x   = (const float*)d_in[0];
  const float* W1  = (const float*)d_in[1];
  const float* b1  = (const float*)d_in[2];
  const float* W2  = (const float*)d_in[3];
  const float* b2  = (const float*)d_in[4];
  const float* dW1 = (const float*)d_in[5];
  const float* db1 = (const float*)d_in[6];
  const float* dW2 = (const float*)d_in[7];
  const float* db2 = (const float*)d_in[8];
  const float* mW1 = (const float*)d_in[9];
  const float* mb1 = (const float*)d_in[10];
  const float* mW2 = (const float*)d_in[11];
  const float* mb2 = (const float*)d_in[12];
  float* out = (float*)d_out;

  float* ws    = (float*)d_ws;
  float* xp    = ws;                 // 150528
  float* z1    = xp + 150528;        // 16384
  float* coefs = z1 + 16384;         // 512
  float* h     = coefs + 512;        // 16384
  float* P1    = h + 16384;          // 112*16*1024 = 1835008
  float* P2    = P1 + 1835008;       // 16*16*512   = 131072
  float* P3    = P2 + 131072;        // 256*16*1024 = 4194304
  float* P4    = P3 + 4194304;       // 288*16*512  = 2359296
  // total ~8.6M floats ~ 34 MB

  // 1) xp = pool(x)
  pool_kernel<<<588, 256, 0, stream>>>(x, xp);

  // 2) gbig6: G3 (256 blocks, UF=14 deep pipeline) + G1 (112 blocks)
  gbig6_kernel<<<368, 256, 0, stream>>>(xp, W1, dW1, P1, P3);

  // 3) rg12: R1 + G2 -> z1, P2
  rg12_kernel<<<256, 256, 0, stream>>>(P1, b1, W2, z1, P2);

  // 4) tail2: R2 + mcoef -> coefs
  tail2_kernel<<<16, 512, 0, stream>>>(P2, b2, mW1, mb1, mW2, mb2, coefs);

  // 5) R3 (cW1 scale per slice) -> h
  reduce4<256, 3, 16384><<<256, 256, 0, stream>>>(P3, z1, coefs, db1, h);

  // 6) G4: h @ {dW2 scaled, W2} -> P4
  skinny_gemm<32, 2, 8, 1, 256><<<dim3(288, 1), 256, 0, stream>>>(
      h, 1024, dW2, h, 1024, W2, 256, 32, coefs + 2, 512, P4);

  // 7) R4 -> out
  reduce4<288, 4, 8192><<<128, 256, 0, stream>>>(P4, b2, coefs, db2, out);
}

// Round 18
// 106.948 us; speedup vs baseline: 1.1490x; 1.0898x over previous
//
#include <hip/hip_runtime.h>
#include <cstdint>
#include <cstddef>

// Sizes: B=16, T=8, K=4, DIN=9408, H1=1024, F=512, MH=128

typedef float f2_t __attribute__((ext_vector_type(2)));
typedef float f4_t __attribute__((ext_vector_type(4)));
typedef unsigned int u2_t __attribute__((ext_vector_type(2)));

// bf16 pack/unpack (round-to-nearest-even), deterministic
__device__ __forceinline__ uint16_t f2bf(float x) {
  uint32_t u = __float_as_uint(x);
  u += 0x7FFF + ((u >> 16) & 1);
  return (uint16_t)(u >> 16);
}
__device__ __forceinline__ float bf2f(uint32_t h16) {   // low 16 bits used
  return __uint_as_float(h16 << 16);
}

// ---------------- 4x4 average pool: x(16,3,224,224) -> xp(16,9408) ----------------
__global__ void pool_kernel(const float* __restrict__ x, float* __restrict__ xp) {
  int idx = blockIdx.x * 256 + threadIdx.x;      // 150528 total
  int bc = idx / 3136;
  int r  = idx - bc * 3136;
  int i  = r / 56;
  int j  = r - i * 56;
  const float* src = x + ((size_t)bc * 224 + 4 * i) * 224 + 4 * j;
  float s = 0.f;
#pragma unroll
  for (int rr = 0; rr < 4; ++rr) {
    float4 v = *reinterpret_cast<const float4*>(src + rr * 224);
    s += v.x + v.y + v.z + v.w;
  }
  xp[idx] = s * 0.0625f;
}

// ---------------- software-pipelined GEMM inner pipe (even AND odd NG) ----------------
template<int KC, int VEC, int UF, int NT>
__device__ __forceinline__ void gemm_pipe(
    const float* a_s, const float* Brow, int N, float (&acc)[16][VEC])
{
  static_assert(KC % UF == 0, "");
  constexpr int NG = KC / UF;
  static_assert(NG >= 2, "");
  float w0[UF][VEC], w1[UF][VEC];

  auto loadg = [&](float (&W)[UF][VEC], int kb) {
#pragma unroll
    for (int u = 0; u < UF; ++u) {
      const float* p = Brow + (size_t)(kb + u) * N;
      if constexpr (VEC == 2) {
        f2_t v;
        if constexpr (NT) v = __builtin_nontemporal_load(reinterpret_cast<const f2_t*>(p));
        else              v = *reinterpret_cast<const f2_t*>(p);
        W[u][0] = v.x; W[u][1] = v.y;
      } else {
        f4_t v;
        if constexpr (NT) v = __builtin_nontemporal_load(reinterpret_cast<const f4_t*>(p));
        else              v = *reinterpret_cast<const f4_t*>(p);
        W[u][0] = v.x; W[u][1] = v.y; W[u][2] = v.z; W[u][3] = v.w;
      }
    }
  };
  auto comp = [&](const float (&W)[UF][VEC], int kb) {
#pragma unroll
    for (int u = 0; u < UF; ++u) {
      int kk = kb + u;
      const float4 a0 = *reinterpret_cast<const float4*>(&a_s[kk * 20 + 0]);
      const float4 a1 = *reinterpret_cast<const float4*>(&a_s[kk * 20 + 4]);
      const float4 a2 = *reinterpret_cast<const float4*>(&a_s[kk * 20 + 8]);
      const float4 a3 = *reinterpret_cast<const float4*>(&a_s[kk * 20 + 12]);
      const float av[16] = {a0.x, a0.y, a0.z, a0.w, a1.x, a1.y, a1.z, a1.w,
                            a2.x, a2.y, a2.z, a2.w, a3.x, a3.y, a3.z, a3.w};
#pragma unroll
      for (int b = 0; b < 16; ++b)
#pragma unroll
        for (int v = 0; v < VEC; ++v)
          acc[b][v] = fmaf(av[b], W[u][v], acc[b][v]);
    }
  };

  loadg(w0, 0);
  if constexpr (NG % 2 == 0) {
#pragma unroll 1
    for (int g = 0; g + 2 < NG; g += 2) {
      loadg(w1, (g + 1) * UF);
      comp(w0, g * UF);
      loadg(w0, (g + 2) * UF);
      comp(w1, (g + 1) * UF);
    }
    loadg(w1, (NG - 1) * UF);
    comp(w0, (NG - 2) * UF);
    comp(w1, (NG - 1) * UF);
  } else {
#pragma unroll 1
    for (int g = 0; g + 3 < NG; g += 2) {
      loadg(w1, (g + 1) * UF);
      comp(w0, g * UF);
      loadg(w0, (g + 2) * UF);
      comp(w1, (g + 1) * UF);
    }
    loadg(w1, (NG - 2) * UF);
    comp(w0, (NG - 3) * UF);
    loadg(w0, (NG - 1) * UF);
    comp(w1, (NG - 2) * UF);
    comp(w0, (NG - 1) * UF);
  }
}

// ---------------- gbig7: R15 champion shape + bf16 P3 stores ----------------
// G3 (256 blocks first): t=c>>5, il=(c&31)*294; KC=294, VEC=4, UF=7 -> P3[c] (bf16).
// G1 (112 blocks): KC=84, VEC=4 -> P1[c] (fp32, feeds z1 precision chain).
__global__ __launch_bounds__(256) void gbig7_kernel(
    const float* __restrict__ xp,
    const float* __restrict__ W1,
    const float* __restrict__ dW1,
    float* __restrict__ P1, uint16_t* __restrict__ P3)
{
  __shared__ float a_s[294 * 20];   // 23.5 KB
  const int tid = threadIdx.x;

  if (blockIdx.x < 256) {
    // ---- G3 chunk ----
    const int c = blockIdx.x;
    const int t = c >> 5, il = (c & 31) * 294;
    for (int idx = tid; idx < 16 * 294; idx += 256) {
      int b = idx / 294, kk = idx - b * 294;
      a_s[kk * 20 + b] = xp[(size_t)b * 9408 + il + kk];
    }
    __syncthreads();

    const int j0 = tid * 4;
    float acc[16][4];
#pragma unroll
    for (int b = 0; b < 16; ++b)
#pragma unroll
      for (int v = 0; v < 4; ++v) acc[b][v] = 0.f;
    gemm_pipe<294, 4, 7, 1>(a_s, dW1 + ((size_t)t * 9408 + il) * 1024 + j0, 1024, acc);

    uint16_t* Pb = P3 + (size_t)c * 16 * 1024 + j0;
#pragma unroll
    for (int b = 0; b < 16; ++b) {
      u2_t v;
      v.x = (uint32_t)f2bf(acc[b][0]) | ((uint32_t)f2bf(acc[b][1]) << 16);
      v.y = (uint32_t)f2bf(acc[b][2]) | ((uint32_t)f2bf(acc[b][3]) << 16);
      __builtin_nontemporal_store(v, reinterpret_cast<u2_t*>(Pb));
      Pb += 1024;
    }
  } else {
    // ---- G1 chunk (fp32 partials) ----
    const int c = blockIdx.x - 256;
    for (int idx = tid; idx < 16 * 84; idx += 256) {
      int b = idx / 84, kk = idx - b * 84;
      a_s[kk * 20 + b] = xp[(size_t)b * 9408 + c * 84 + kk];
    }
    __syncthreads();

    const int j0 = tid * 4;
    float acc[16][4];
#pragma unroll
    for (int b = 0; b < 16; ++b)
#pragma unroll
      for (int v = 0; v < 4; ++v) acc[b][v] = 0.f;
    gemm_pipe<84, 4, 7, 1>(a_s, W1 + (size_t)c * 84 * 1024 + j0, 1024, acc);

    float* Pb = P1 + (size_t)c * 16 * 1024 + j0;
#pragma unroll
    for (int b = 0; b < 16; ++b) {
      f4_t v = {acc[b][0], acc[b][1], acc[b][2], acc[b][3]};
      __builtin_nontemporal_store(v, reinterpret_cast<f4_t*>(Pb));
      Pb += 1024;
    }
  }
}

// ---------------- rg12: R1 + G2 fused. 256 blocks x 256 thr (fp32 P1) ----------------
__global__ __launch_bounds__(256) void rg12_kernel(
    const float* __restrict__ P1, const float* __restrict__ b1,
    const float* __restrict__ W2,
    float* __restrict__ z1, float* __restrict__ P2)
{
  __shared__ float4 r[16][17];
  __shared__ float t1s[64];
  const int blk = blockIdx.x;
  const int b = blk >> 4, jg = blk & 15;
  const int fl = threadIdx.x & 15, s = threadIdx.x >> 4;
  const int f = blk * 64 + fl * 4;          // = b*1024 + jg*64 + fl*4

  const f4_t* p = reinterpret_cast<const f4_t*>(P1 + (size_t)s * 7 * 16384 + f);
  float sx = 0.f, sy = 0.f, sz = 0.f, sw = 0.f;
#pragma unroll
  for (int cc = 0; cc < 7; ++cc) {
    f4_t v = __builtin_nontemporal_load(p);
    sx += v.x; sy += v.y; sz += v.z; sw += v.w;
    p += 4096;                              // 16384/4
  }
  r[s][fl] = make_float4(sx, sy, sz, sw);
  __syncthreads();

  if (s == 0) {
    float vx = 0.f, vy = 0.f, vz = 0.f, vw = 0.f;
#pragma unroll
    for (int i = 0; i < 16; ++i) {
      float4 t = r[i][fl];
      vx += t.x; vy += t.y; vz += t.z; vw += t.w;
    }
    float4 bb = *reinterpret_cast<const float4*>(b1 + (f & 1023));
    float4 z = make_float4(vx + bb.x, vy + bb.y, vz + bb.z, vw + bb.w);
    *reinterpret_cast<float4*>(z1 + f) = z;
    *reinterpret_cast<float4*>(&t1s[fl * 4]) =
        make_float4(fmaxf(z.x, 0.f), fmaxf(z.y, 0.f), fmaxf(z.z, 0.f), fmaxf(z.w, 0.f));
  }
  __syncthreads();

  const int j = threadIdx.x * 2;
  const float* w = W2 + (size_t)(jg * 64) * 512 + j;
  float a0 = 0.f, a1 = 0.f;
#pragma unroll 8
  for (int kk = 0; kk < 64; ++kk) {
    f2_t wv = *reinterpret_cast<const f2_t*>(w);
    w += 512;
    float tv = t1s[kk];
    a0 = fmaf(tv, wv.x, a0);
    a1 = fmaf(tv, wv.y, a1);
  }
  f2_t o = {a0, a1};
  __builtin_nontemporal_store(o, reinterpret_cast<f2_t*>(P2 + ((size_t)jg * 16 + b) * 512 + j));
}

// ---------------- split-K skinny GEMM (M=16), bf16 partial stores -- used for G4 ------
template<int KC, int UF, int BS>
__global__ __launch_bounds__(BS) void skinny_gemm_bf(
    const float* __restrict__ A, int ldA,
    const float* __restrict__ B,
    const float* __restrict__ A2, int ldA2,
    const float* __restrict__ B2,
    int chunkSplit, int chunksPerT,
    const float* __restrict__ coefs4,
    int N, uint16_t* __restrict__ P)
{
  __shared__ float a_s[KC * 20];
  const int c = blockIdx.x, tid = threadIdx.x;

  const float* Ab;
  const float* Bb;
  int lda, iLoc0, t = 0;
  bool scaled = false;
  if (c < chunkSplit) {
    Ab = A; lda = ldA;
    if (chunksPerT > 0) {
      t = c / chunksPerT;
      iLoc0 = (c - t * chunksPerT) * KC;
    } else {
      iLoc0 = c * KC;
    }
    scaled = (coefs4 != nullptr);
    Bb = B + (size_t)c * KC * N;
  } else {
    Ab = A2; lda = ldA2;
    iLoc0 = (c - chunkSplit) * KC;
    Bb = B2 + (size_t)iLoc0 * N;
  }

  for (int b = 0; b < 16; ++b) {
    float s = scaled ? coefs4[b * 32 + t * 4] : 1.f;
    const float* Arow = Ab + (size_t)b * lda + iLoc0;
    for (int kk = tid; kk < KC; kk += BS)
      a_s[kk * 20 + b] = s * Arow[kk];
  }
  __syncthreads();

  const int j0 = tid * 2;
  float acc[16][2];
#pragma unroll
  for (int b = 0; b < 16; ++b) { acc[b][0] = 0.f; acc[b][1] = 0.f; }

  gemm_pipe<KC, 2, UF, 1>(a_s, Bb + j0, N, acc);

  uint16_t* Pb = P + (size_t)c * 16 * N + j0;
#pragma unroll
  for (int b = 0; b < 16; ++b) {
    uint32_t v = (uint32_t)f2bf(acc[b][0]) | ((uint32_t)f2bf(acc[b][1]) << 16);
    __builtin_nontemporal_store(v, reinterpret_cast<uint32_t*>(Pb));
    Pb += N;
  }
}

// ---------------- fused reduce + epilogue (bf16 P, 16 slices x 16 cols) ------
// MODE 3: h=relu(z1+cW1-scaled-sum+db1 term)   MODE 4: out
template<int NCH, int MODE, int FTOT>
__global__ __launch_bounds__(256) void reduce4bf(
    const uint16_t* __restrict__ P,
    const float* __restrict__ bias,      // z1(M3), b2(M4)
    const float* __restrict__ coefs,
    const float* __restrict__ dvec,      // db1(M3), db2(M4)
    float* __restrict__ o1)
{
  constexpr int CPS = NCH / 16;
  static_assert(NCH % 16 == 0, "");
  __shared__ float4 r[16][17];
  const int fl = threadIdx.x & 15, s = threadIdx.x >> 4;
  const int f = blockIdx.x * 64 + fl * 4;

  const u2_t* p = reinterpret_cast<const u2_t*>(P + (size_t)s * CPS * FTOT + f);
  float sx = 0.f, sy = 0.f, sz = 0.f, sw = 0.f;
#pragma unroll 8
  for (int cc = 0; cc < CPS; ++cc) {
    u2_t v = __builtin_nontemporal_load(p);
    sx += bf2f(v.x & 0xFFFFu); sy += bf2f(v.x >> 16);
    sz += bf2f(v.y & 0xFFFFu); sw += bf2f(v.y >> 16);
    p += FTOT / 4;                     // one chunk = FTOT bf16 = FTOT/4 u2_t
  }
  if constexpr (MODE == 3) {
    int b = f >> 10;
    float sc = coefs[b * 32 + (s >> 1) * 4];   // cW1[b, t = s/2] (32 chunks/t = 2 slices/t)
    sx *= sc; sy *= sc; sz *= sc; sw *= sc;
  }
  r[s][fl] = make_float4(sx, sy, sz, sw);
  __syncthreads();

  if (s == 0) {
    float vx = 0.f, vy = 0.f, vz = 0.f, vw = 0.f;
#pragma unroll
    for (int i = 0; i < 16; ++i) {
      float4 t = r[i][fl];
      vx += t.x; vy += t.y; vz += t.z; vw += t.w;
    }
    if constexpr (MODE == 3) {
      int b = f >> 10, j = f & 1023;
      float4 zz = *reinterpret_cast<const float4*>(bias + f);   // z1
      float zx = vx + zz.x, zy = vy + zz.y, zzc = vz + zz.z, zw = vw + zz.w;
#pragma unroll
      for (int t = 0; t < 8; ++t) {
        float c1 = coefs[b * 32 + t * 4 + 1];
        float4 d = *reinterpret_cast<const float4*>(dvec + t * 1024 + j);
        zx = fmaf(c1, d.x, zx); zy = fmaf(c1, d.y, zy);
        zzc = fmaf(c1, d.z, zzc); zw = fmaf(c1, d.w, zw);
      }
      *reinterpret_cast<float4*>(o1 + f) =
          make_float4(fmaxf(zx, 0.f), fmaxf(zy, 0.f), fmaxf(zzc, 0.f), fmaxf(zw, 0.f));
    } else {
      int b = f >> 9, k = f & 511;
      float4 bb = *reinterpret_cast<const float4*>(bias + k);   // b2
      float zx = vx + bb.x, zy = vy + bb.y, zzc = vz + bb.z, zw = vw + bb.w;
#pragma unroll
      for (int t = 0; t < 8; ++t) {
        float c3 = coefs[b * 32 + t * 4 + 3];
        float4 d = *reinterpret_cast<const float4*>(dvec + t * 512 + k);
        zx = fmaf(c3, d.x, zx); zy = fmaf(c3, d.y, zy);
        zzc = fmaf(c3, d.z, zzc); zw = fmaf(c3, d.w, zw);
      }
      *reinterpret_cast<float4*>(o1 + f) = make_float4(zx, zy, zzc, zw);
    }
  }
}

// ---------------- tail2: R2 + mcoef fused. One block per b (16 x 512 thr). ----------
__global__ __launch_bounds__(512) void tail2_kernel(
    const float* __restrict__ P2, const float* __restrict__ b2,
    const float* __restrict__ mW1, const float* __restrict__ mb1,
    const float* __restrict__ mW2, const float* __restrict__ mb2,
    float* __restrict__ coefs)
{
  __shared__ float bs[512];
  __shared__ float pm[4][129];
  __shared__ float ms[128];
  __shared__ float p3[16][33];
  const int b = blockIdx.x, tid = threadIdx.x;

  // phase 1: base[b][k] = b2[k] + sum over 16 chunks
  float s = b2[tid];
  const float* p = P2 + b * 512 + tid;
#pragma unroll
  for (int c = 0; c < 16; ++c) { s += *p; p += 8192; }
  bs[tid] = s;
  __syncthreads();

  // phase 2: m[col], k-split 4 ways
  {
    int col = tid & 127, kq = tid >> 7;
    const float* br = &bs[kq * 128];
    const float* w = mW1 + (size_t)(kq * 128) * 128 + col;
    float m0 = 0.f, m1 = 0.f, m2 = 0.f, m3 = 0.f;
    for (int k = 0; k < 128; k += 4) {
      m0 = fmaf(br[k + 0], w[(k + 0) * 128], m0);
      m1 = fmaf(br[k + 1], w[(k + 1) * 128], m1);
      m2 = fmaf(br[k + 2], w[(k + 2) * 128], m2);
      m3 = fmaf(br[k + 3], w[(k + 3) * 128], m3);
    }
    pm[kq][col] = (m0 + m1) + (m2 + m3);
  }
  __syncthreads();
  if (tid < 128)
    ms[tid] = fmaxf(mb1[tid] + (pm[0][tid] + pm[1][tid]) + (pm[2][tid] + pm[3][tid]), 0.f);
  __syncthreads();

  // phase 3: coefs[o], k-split 16 ways
  {
    int o = tid & 31, kq = tid >> 5;
    float a = 0.f;
#pragma unroll
    for (int kk = 0; kk < 8; ++kk)
      a = fmaf(ms[kq * 8 + kk], mW2[(kq * 8 + kk) * 32 + o], a);
    p3[kq][o] = a;
  }
  __syncthreads();
  if (tid < 32) {
    float a = mb2[tid];
#pragma unroll
    for (int q = 0; q < 16; ++q) a += p3[q][tid];
    coefs[b * 32 + tid] = a;
  }
}

extern "C" void kernel_launch(void* const* d_in, const int* in_sizes, int n_in,
                              void* d_out, int out_size, void* d_ws, size_t ws_size,
                              hipStream_t stream) {
  const float* x   = (const float*)d_in[0];
  const float* W1  = (const float*)d_in[1];
  const float* b1  = (const float*)d_in[2];
  const float* W2  = (const float*)d_in[3];
  const float* b2  = (const float*)d_in[4];
  const float* dW1 = (const float*)d_in[5];
  const float* db1 = (const float*)d_in[6];
  const float* dW2 = (const float*)d_in[7];
  const float* db2 = (const float*)d_in[8];
  const float* mW1 = (const float*)d_in[9];
  const float* mb1 = (const float*)d_in[10];
  const float* mW2 = (const float*)d_in[11];
  const float* mb2 = (const float*)d_in[12];
  float* out = (float*)d_out;

  float* ws    = (float*)d_ws;
  float* xp    = ws;                   // 150528
  float* z1    = xp + 150528;          // 16384
  float* coefs = z1 + 16384;           // 512
  float* h     = coefs + 512;          // 16384
  float* P1    = h + 16384;            // 112*16*1024 = 1835008 floats
  float* P2    = P1 + 1835008;         // 16*16*512   = 131072 floats
  uint16_t* P3 = (uint16_t*)(P2 + 131072);        // 256*16*1024 = 4194304 bf16
  uint16_t* P4 = P3 + 4194304;                    // 288*16*512  = 2359296 bf16
  // total ~2.15M + 4.4M floats-equiv ~ 26 MB

  // 1) xp = pool(x)
  pool_kernel<<<588, 256, 0, stream>>>(x, xp);

  // 2) gbig7: R15 champion (G3 256 blocks KC=294 VEC=4 UF=7 + G1 112) + bf16 P3
  gbig7_kernel<<<368, 256, 0, stream>>>(xp, W1, dW1, P1, P3);

  // 3) rg12: R1 + G2 -> z1, P2
  rg12_kernel<<<256, 256, 0, stream>>>(P1, b1, W2, z1, P2);

  // 4) tail2: R2 + mcoef -> coefs
  tail2_kernel<<<16, 512, 0, stream>>>(P2, b2, mW1, mb1, mW2, mb2, coefs);

  // 5) R3 (cW1 scale per slice, bf16 P3) -> h
  reduce4bf<256, 3, 16384><<<256, 256, 0, stream>>>(P3, z1, coefs, db1, h);

  // 6) G4: h @ {dW2 scaled, W2} -> P4 (bf16)
  skinny_gemm_bf<32, 8, 256><<<dim3(288, 1), 256, 0, stream>>>(
      h, 1024, dW2, h, 1024, W2, 256, 32, coefs + 2, 512, P4);

  // 7) R4 (bf16 P4) -> out
  reduce4bf<288, 4, 8192><<<128, 256, 0, stream>>>(P4, b2, coefs, db2, out);
}